// Round 19
// baseline (539.910 us; speedup 1.0000x reference)
//
#include <hip/hip_runtime.h>
#include <hip/hip_bf16.h>

#define HID 64

typedef float f32x4 __attribute__((ext_vector_type(4)));

// ---- bf16 helpers ----
__device__ __forceinline__ unsigned short f2bf(float f) {  // RNE f32->bf16
    unsigned u = __float_as_uint(f);
    return (unsigned short)((u + 0x7fffu + ((u >> 16) & 1u)) >> 16);
}
// a[0..7] += bf16x8 packed in uint4 (low ushort = even feat)
__device__ __forceinline__ void acc8(float* a, uint4 v) {
    a[0] += __uint_as_float(v.x << 16);
    a[1] += __uint_as_float(v.x & 0xffff0000u);
    a[2] += __uint_as_float(v.y << 16);
    a[3] += __uint_as_float(v.y & 0xffff0000u);
    a[4] += __uint_as_float(v.z << 16);
    a[5] += __uint_as_float(v.z & 0xffff0000u);
    a[6] += __uint_as_float(v.w << 16);
    a[7] += __uint_as_float(v.w & 0xffff0000u);
}

// ================= CSR build (by dst) =================

__global__ __launch_bounds__(256) void hist_part_kernel(
    const int* __restrict__ dst, int* __restrict__ cnt, int E, int psz) {
    int part = blockIdx.x & 7, chunk = blockIdx.x >> 3;
    int i = chunk * 256 + threadIdx.x;
    if (i >= E) return;
    int d = __builtin_nontemporal_load(&dst[i]);
    if (d / psz == part) atomicAdd(&cnt[d], 1);
}

__global__ __launch_bounds__(256) void bsum_kernel(const int* __restrict__ cnt,
                                                   int* __restrict__ bsums, int N) {
    __shared__ int s[256];
    int tid = threadIdx.x, i = blockIdx.x * 256 + tid;
    s[tid] = (i < N) ? cnt[i] : 0;
    __syncthreads();
    for (int o = 128; o > 0; o >>= 1) {
        if (tid < o) s[tid] += s[tid + o];
        __syncthreads();
    }
    if (tid == 0) bsums[blockIdx.x] = s[0];
}

__global__ __launch_bounds__(512) void scan_bsums_kernel(int* __restrict__ bsums, int nblk) {
    __shared__ int s[512];
    int tid = threadIdx.x;
    int orig = (tid < nblk) ? bsums[tid] : 0;
    s[tid] = orig;
    __syncthreads();
    for (int off = 1; off < 512; off <<= 1) {
        int v = (tid >= off) ? s[tid - off] : 0;
        __syncthreads();
        s[tid] += v;
        __syncthreads();
    }
    if (tid < nblk) bsums[tid] = s[tid] - orig;
}

// nodeinfo[n] = {row_ptr, deg, bits(dinv), 0}
__global__ __launch_bounds__(256) void rowptr_kernel(
    const int* __restrict__ cnt, const int* __restrict__ bsums,
    int4* __restrict__ nodeinfo, int* __restrict__ cursor, int N) {
    __shared__ int s[256];
    int tid = threadIdx.x, i = blockIdx.x * 256 + tid;
    int c = (i < N) ? cnt[i] : 0;
    s[tid] = c;
    __syncthreads();
    for (int off = 1; off < 256; off <<= 1) {
        int v = (tid >= off) ? s[tid - off] : 0;
        __syncthreads();
        s[tid] += v;
        __syncthreads();
    }
    if (i < N) {
        int excl = s[tid] - c + bsums[blockIdx.x];
        cursor[i] = excl;
        int4 ni;
        ni.x = excl;
        ni.y = c;
        ni.z = (int)__float_as_uint(rsqrtf((float)c + 1.0f));  // +1 self-loop
        ni.w = 0;
        nodeinfo[i] = ni;
    }
}

__global__ __launch_bounds__(256) void fill_part_kernel(
    const int* __restrict__ src, const int* __restrict__ dst,
    int* __restrict__ cursor, int* __restrict__ col, int E, int psz) {
    int part = blockIdx.x & 7, chunk = blockIdx.x >> 3;
    int i = chunk * 256 + threadIdx.x;
    if (i >= E) return;
    int d = __builtin_nontemporal_load(&dst[i]);
    if (d / psz == part) {
        int s = __builtin_nontemporal_load(&src[i]);
        int p = atomicAdd(&cursor[d], 1);
        col[p] = s;
    }
}

// ================= dual gather core (r15-proven) =================
// TWO nodes per wave, interleaved: 2 independent load chains per lane; one
// node's VALU hides the other's latency. Self-loop added after the reduce.
__device__ __forceinline__ void gather64_dual(
    const uint4* __restrict__ g4, const int* __restrict__ col,
    int beg0, int deg0, int c0, int n0,
    int beg1, int deg1, int c1, int n1,
    int N, int lane, float* t0, float* t1) {
    int eighth = lane >> 3, fo = lane & 7;
    float A0[8] = {}, A1[8] = {};
    int dmax = deg0 > deg1 ? deg0 : deg1;
    int base = 0;
    while (true) {
        int rm = dmax - base; if (rm > 64) rm = 64;
        int gm = (rm + 7) >> 3;
        for (int j = 0; j < gm; ++j) {
            int s0 = __shfl(c0, 8 * j + eighth, 64);
            int s1 = __shfl(c1, 8 * j + eighth, 64);
            uint4 v0 = g4[(size_t)s0 * 8 + fo];
            uint4 v1 = g4[(size_t)s1 * 8 + fo];
            acc8(A0, v0);
            acc8(A1, v1);
        }
        base += 64;
        if (base >= dmax) break;
        c0 = (lane < deg0 - base) ? __builtin_nontemporal_load(&col[beg0 + base + lane]) : N;
        c1 = (lane < deg1 - base) ? __builtin_nontemporal_load(&col[beg1 + base + lane]) : N;
    }
    // self-loop rows: added ONCE, after the reduce
    float sf0[8] = {}, sf1[8] = {};
    acc8(sf0, g4[(size_t)n0 * 8 + fo]);
    acc8(sf1, g4[(size_t)n1 * 8 + fo]);
#pragma unroll
    for (int k = 0; k < 8; ++k) {
        float s0 = A0[k], s1 = A1[k];
        s0 += __shfl_xor(s0, 8, 64);
        s1 += __shfl_xor(s1, 8, 64);
        s0 += __shfl_xor(s0, 16, 64);
        s1 += __shfl_xor(s1, 16, 64);
        s0 += __shfl_xor(s0, 32, 64);
        s1 += __shfl_xor(s1, 32, 64);
        t0[k] = s0 + sf0[k];
        t1[k] = s1 + sf1[k];
    }
}

// ================= conv1 GEMM: g = bf16((X@W)*dinv) — exact grid ===========

__global__ __launch_bounds__(256) void gemm_scale_kernel(
    const float* __restrict__ X, const float* __restrict__ W,
    const int4* __restrict__ nodeinfo, unsigned short* __restrict__ g, int N) {
    __shared__ float Ws[HID * HID];
    __shared__ float xs[4][HID];
    int tid = threadIdx.x;
    for (int i = tid; i < HID * HID; i += 256) Ws[i] = W[i];
    __syncthreads();
    int w = tid >> 6, c = tid & 63;
    float* xsw = xs[w];
    int row = blockIdx.x * 4 + w;
    if (row >= N) return;
    xsw[c] = __builtin_nontemporal_load(&X[(size_t)row * HID + c]);
    float dn = __uint_as_float((unsigned)__builtin_amdgcn_readfirstlane(nodeinfo[row].z));
    float acc = 0.f;
#pragma unroll
    for (int k = 0; k < HID; ++k) acc = fmaf(xsw[k], Ws[k * HID + c], acc);
    __builtin_nontemporal_store(f2bf(acc * dn), &g[(size_t)row * HID + c]);
}

// ---- register 8x8-block GEMM butterfly (r14-proven) ----
__device__ __forceinline__ float reggemm_butterfly(
    const unsigned* Wp, const float* o, int s) {
    float p[8] = {};
#pragma unroll
    for (int j = 0; j < 8; ++j) {
        float oj = o[j];
#pragma unroll
        for (int i2 = 0; i2 < 4; ++i2) {
            unsigned wv = Wp[j * 4 + i2];
            p[2 * i2]     = fmaf(oj, __uint_as_float(wv << 16), p[2 * i2]);
            p[2 * i2 + 1] = fmaf(oj, __uint_as_float(wv & 0xffff0000u), p[2 * i2 + 1]);
        }
    }
    bool b0 = (s & 1) != 0;
    float q1[4];
#pragma unroll
    for (int m = 0; m < 4; ++m) {
        float A = __shfl_xor(p[2 * m], 1, 64);
        float B = __shfl_xor(p[2 * m + 1], 1, 64);
        q1[m] = b0 ? (p[2 * m + 1] + B) : (p[2 * m] + A);
    }
    bool b1 = ((s >> 1) & 1) != 0;
    float q2[2];
#pragma unroll
    for (int m = 0; m < 2; ++m) {
        float A = __shfl_xor(q1[2 * m], 2, 64);
        float B = __shfl_xor(q1[2 * m + 1], 2, 64);
        q2[m] = b1 ? (q1[2 * m + 1] + B) : (q1[2 * m] + A);
    }
    bool b2 = ((s >> 2) & 1) != 0;
    float A = __shfl_xor(q2[0], 4, 64);
    float B = __shfl_xor(q2[1], 4, 64);
    return b2 ? (q2[1] + B) : (q2[0] + A);
}

// ================= fused aggregate + epilogue + next-conv GEMM =============
// 2 nodes/wave, (256,4) [r15 config]; exact grid (no grid-stride) so the HW
// dispatcher dynamically backfills CUs as blocks retire.

template <bool RELU>
__global__ __launch_bounds__(256, 4) void agg_gemm_kernel(
    const unsigned short* __restrict__ g_in, const int4* __restrict__ nodeinfo,
    const int* __restrict__ col, const float* __restrict__ bias,
    const float* __restrict__ W, unsigned short* __restrict__ g_out, int N) {
    int tid = threadIdx.x, w = tid >> 6, lane = tid & 63;
    int s = lane & 7;
    unsigned Wp[32];
#pragma unroll
    for (int j = 0; j < 8; ++j)
#pragma unroll
        for (int i2 = 0; i2 < 4; ++i2) {
            float w0 = W[(8 * s + j) * HID + 8 * (lane >> 3) + 2 * i2];
            float w1 = W[(8 * s + j) * HID + 8 * (lane >> 3) + 2 * i2 + 1];
            Wp[j * 4 + i2] = (unsigned)f2bf(w0) | ((unsigned)f2bf(w1) << 16);
        }
    float bb[8];
#pragma unroll
    for (int j = 0; j < 8; ++j) bb[j] = bias[8 * s + j];
    const uint4* g4 = (const uint4*)g_in;
    int grp = blockIdx.x;
    int n0 = grp * 8 + w;
    int n1 = n0 + 4;
    if (n0 >= N) return;
    bool has1 = n1 < N;
    int4 ni0 = nodeinfo[n0];
    int4 ni1 = has1 ? nodeinfo[n1] : ni0;
    int beg0 = __builtin_amdgcn_readfirstlane(ni0.x);
    int deg0 = __builtin_amdgcn_readfirstlane(ni0.y);
    float dn0 = __uint_as_float((unsigned)__builtin_amdgcn_readfirstlane(ni0.z));
    int beg1 = __builtin_amdgcn_readfirstlane(ni1.x);
    int deg1 = has1 ? __builtin_amdgcn_readfirstlane(ni1.y) : 0;
    float dn1 = __uint_as_float((unsigned)__builtin_amdgcn_readfirstlane(ni1.z));
    int c0 = (lane < deg0) ? __builtin_nontemporal_load(&col[beg0 + lane]) : N;
    int c1 = (lane < deg1) ? __builtin_nontemporal_load(&col[beg1 + lane]) : N;
    float t0[8], t1[8];
    gather64_dual(g4, col, beg0, deg0, c0, n0, beg1, deg1, c1, has1 ? n1 : N,
                  N, lane, t0, t1);
    float o[8];
#pragma unroll
    for (int j = 0; j < 8; ++j) {
        o[j] = fmaf(dn0, t0[j], bb[j]);
        if (RELU) o[j] = fmaxf(o[j], 0.f);
    }
    float r0 = reggemm_butterfly(Wp, o, s);
    __builtin_nontemporal_store(f2bf(r0 * dn0), &g_out[(size_t)n0 * HID + lane]);
    if (has1) {
#pragma unroll
        for (int j = 0; j < 8; ++j) {
            o[j] = fmaf(dn1, t1[j], bb[j]);
            if (RELU) o[j] = fmaxf(o[j], 0.f);
        }
        float r1 = reggemm_butterfly(Wp, o, s);
        __builtin_nontemporal_store(f2bf(r1 * dn1), &g_out[(size_t)n1 * HID + lane]);
    }
}

// ================= final aggregate + bias + log_softmax (2 nodes/wave) =====

__device__ __forceinline__ void lsm_store(
    const float* t, float dn, const float* bb, int n, int lane, float* out) {
    int eighth = lane >> 3, fo = lane & 7;
    float v[8];
#pragma unroll
    for (int k = 0; k < 8; ++k) v[k] = fmaf(dn, t[k], bb[k]);
    float mx = v[0];
#pragma unroll
    for (int k = 1; k < 8; ++k) mx = fmaxf(mx, v[k]);
    mx = fmaxf(mx, __shfl_xor(mx, 1, 64));
    mx = fmaxf(mx, __shfl_xor(mx, 2, 64));
    mx = fmaxf(mx, __shfl_xor(mx, 4, 64));
    float sum = 0.f;
#pragma unroll
    for (int k = 0; k < 8; ++k) sum += expf(v[k] - mx);
    sum += __shfl_xor(sum, 1, 64);
    sum += __shfl_xor(sum, 2, 64);
    sum += __shfl_xor(sum, 4, 64);
    float ls = mx + logf(sum);
    if (eighth == 0) {
        f32x4 o0 = {v[0] - ls, v[1] - ls, v[2] - ls, v[3] - ls};
        f32x4 o1 = {v[4] - ls, v[5] - ls, v[6] - ls, v[7] - ls};
        f32x4* op = (f32x4*)out;
        __builtin_nontemporal_store(o0, &op[(size_t)n * 16 + 2 * fo]);
        __builtin_nontemporal_store(o1, &op[(size_t)n * 16 + 2 * fo + 1]);
    }
}

__global__ __launch_bounds__(256, 4) void agg_lsm_kernel(
    const unsigned short* __restrict__ g_in, const int4* __restrict__ nodeinfo,
    const int* __restrict__ col, const float* __restrict__ bias,
    float* __restrict__ out, int N) {
    int tid = threadIdx.x, w = tid >> 6, lane = tid & 63;
    int fo = lane & 7;
    const uint4* g4 = (const uint4*)g_in;
    float bb[8];
#pragma unroll
    for (int j = 0; j < 8; ++j) bb[j] = bias[8 * fo + j];
    int grp = blockIdx.x;
    int n0 = grp * 8 + w;
    int n1 = n0 + 4;
    if (n0 >= N) return;
    bool has1 = n1 < N;
    int4 ni0 = nodeinfo[n0];
    int4 ni1 = has1 ? nodeinfo[n1] : ni0;
    int beg0 = __builtin_amdgcn_readfirstlane(ni0.x);
    int deg0 = __builtin_amdgcn_readfirstlane(ni0.y);
    float dn0 = __uint_as_float((unsigned)__builtin_amdgcn_readfirstlane(ni0.z));
    int beg1 = __builtin_amdgcn_readfirstlane(ni1.x);
    int deg1 = has1 ? __builtin_amdgcn_readfirstlane(ni1.y) : 0;
    float dn1 = __uint_as_float((unsigned)__builtin_amdgcn_readfirstlane(ni1.z));
    int c0 = (lane < deg0) ? __builtin_nontemporal_load(&col[beg0 + lane]) : N;
    int c1 = (lane < deg1) ? __builtin_nontemporal_load(&col[beg1 + lane]) : N;
    float t0[8], t1[8];
    gather64_dual(g4, col, beg0, deg0, c0, n0, beg1, deg1, c1, has1 ? n1 : N,
                  N, lane, t0, t1);
    lsm_store(t0, dn0, bb, n0, lane, out);
    if (has1) lsm_store(t1, dn1, bb, n1, lane, out);
}

// ================= launcher =================

static inline size_t alignup(size_t x) { return (x + 255) & ~(size_t)255; }

extern "C" void kernel_launch(void* const* d_in, const int* in_sizes, int n_in,
                              void* d_out, int out_size, void* d_ws, size_t ws_size,
                              hipStream_t stream) {
    const float* x  = (const float*)d_in[0];
    const int*   ei = (const int*)d_in[1];
    const float* W1 = (const float*)d_in[2];
    const float* b1 = (const float*)d_in[3];
    const float* W2 = (const float*)d_in[4];
    const float* b2 = (const float*)d_in[5];

    const int N = in_sizes[0] / HID;  // 100000
    const int E = in_sizes[1] / 2;    // 1600000
    const int* src = ei;
    const int* dst = ei + E;

    const int nblk = (N + 255) / 256;  // 391 (<=512 required by scan)
    const int psz  = (N + 7) / 8;      // dst-range partition size

    char* w = (char*)d_ws;
    unsigned short* gA       = (unsigned short*)w; w += alignup((size_t)(N + 1) * HID * 2);
    unsigned short* gB       = (unsigned short*)w; w += alignup((size_t)(N + 1) * HID * 2);
    int4*           nodeinfo = (int4*)w;           w += alignup((size_t)N * 16);
    int*            cnt      = (int*)w;            w += alignup((size_t)N * 4);
    int*            cursor   = (int*)w;            w += alignup((size_t)N * 4);
    int*            col      = (int*)w;            w += alignup((size_t)E * 4);
    int*            bsums    = (int*)w;            w += alignup((size_t)nblk * 4);

    const int egrid = (E + 255) / 256;
    const int ggrid = (N + 3) / 4;     // gemm exact grid
    const int agrid = (N + 7) / 8;     // agg kernels exact grid (8 nodes/block)

    // sentinel rows (index N) of both g buffers: zero once per launch
    (void)hipMemsetAsync(gA + (size_t)N * HID, 0, HID * sizeof(unsigned short), stream);
    (void)hipMemsetAsync(gB + (size_t)N * HID, 0, HID * sizeof(unsigned short), stream);

    // ---- CSR build (once; reused by all 3 convs) ----
    (void)hipMemsetAsync(cnt, 0, (size_t)N * sizeof(int), stream);
    hist_part_kernel<<<egrid * 8, 256, 0, stream>>>(dst, cnt, E, psz);
    bsum_kernel<<<nblk, 256, 0, stream>>>(cnt, bsums, N);
    scan_bsums_kernel<<<1, 512, 0, stream>>>(bsums, nblk);
    rowptr_kernel<<<nblk, 256, 0, stream>>>(cnt, bsums, nodeinfo, cursor, N);
    fill_part_kernel<<<egrid * 8, 256, 0, stream>>>(src, dst, cursor, col, E, psz);

    // ---- conv1 GEMM: gA = (x@W1)*dinv ----
    gemm_scale_kernel<<<ggrid, 256, 0, stream>>>(x, W1, nodeinfo, gA, N);
    // ---- conv1 agg + b1 | conv2 GEMM: gB = ((agg(gA)+b1)@W1)*dinv ----
    agg_gemm_kernel<false><<<agrid, 256, 0, stream>>>(gA, nodeinfo, col, b1, W1, gB, N);
    // ---- conv2 agg + b1 + relu | conv3 GEMM: gA = (relu(agg(gB)+b1)@W2)*dinv ----
    agg_gemm_kernel<true><<<agrid, 256, 0, stream>>>(gB, nodeinfo, col, b1, W2, gA, N);
    // ---- conv3 agg + b2 + log_softmax -> d_out ----
    agg_lsm_kernel<<<agrid, 256, 0, stream>>>(gA, nodeinfo, col, b2, (float*)d_out, N);
}

// Round 20
// 404.288 us; speedup vs baseline: 1.3355x; 1.3355x over previous
//
#include <hip/hip_runtime.h>
#include <hip/hip_bf16.h>

#define HID 64

typedef float f32x4 __attribute__((ext_vector_type(4)));

// ---- bf16 helpers ----
__device__ __forceinline__ unsigned short f2bf(float f) {  // RNE f32->bf16
    unsigned u = __float_as_uint(f);
    return (unsigned short)((u + 0x7fffu + ((u >> 16) & 1u)) >> 16);
}
// a[0..7] += bf16x8 packed in uint4 (low ushort = even feat)
__device__ __forceinline__ void acc8(float* a, uint4 v) {
    a[0] += __uint_as_float(v.x << 16);
    a[1] += __uint_as_float(v.x & 0xffff0000u);
    a[2] += __uint_as_float(v.y << 16);
    a[3] += __uint_as_float(v.y & 0xffff0000u);
    a[4] += __uint_as_float(v.z << 16);
    a[5] += __uint_as_float(v.z & 0xffff0000u);
    a[6] += __uint_as_float(v.w << 16);
    a[7] += __uint_as_float(v.w & 0xffff0000u);
}

// ================= CSR build (by dst) =================

__global__ __launch_bounds__(256) void hist_part_kernel(
    const int* __restrict__ dst, int* __restrict__ cnt, int E, int psz) {
    int part = blockIdx.x & 7, chunk = blockIdx.x >> 3;
    int i = chunk * 256 + threadIdx.x;
    if (i >= E) return;
    int d = __builtin_nontemporal_load(&dst[i]);
    if (d / psz == part) atomicAdd(&cnt[d], 1);
}

__global__ __launch_bounds__(256) void bsum_kernel(const int* __restrict__ cnt,
                                                   int* __restrict__ bsums, int N) {
    __shared__ int s[256];
    int tid = threadIdx.x, i = blockIdx.x * 256 + tid;
    s[tid] = (i < N) ? cnt[i] : 0;
    __syncthreads();
    for (int o = 128; o > 0; o >>= 1) {
        if (tid < o) s[tid] += s[tid + o];
        __syncthreads();
    }
    if (tid == 0) bsums[blockIdx.x] = s[0];
}

__global__ __launch_bounds__(512) void scan_bsums_kernel(int* __restrict__ bsums, int nblk) {
    __shared__ int s[512];
    int tid = threadIdx.x;
    int orig = (tid < nblk) ? bsums[tid] : 0;
    s[tid] = orig;
    __syncthreads();
    for (int off = 1; off < 512; off <<= 1) {
        int v = (tid >= off) ? s[tid - off] : 0;
        __syncthreads();
        s[tid] += v;
        __syncthreads();
    }
    if (tid < nblk) bsums[tid] = s[tid] - orig;
}

// nodeinfo[n] = {row_ptr, deg, bits(dinv), 0}
__global__ __launch_bounds__(256) void rowptr_kernel(
    const int* __restrict__ cnt, const int* __restrict__ bsums,
    int4* __restrict__ nodeinfo, int* __restrict__ cursor, int N) {
    __shared__ int s[256];
    int tid = threadIdx.x, i = blockIdx.x * 256 + tid;
    int c = (i < N) ? cnt[i] : 0;
    s[tid] = c;
    __syncthreads();
    for (int off = 1; off < 256; off <<= 1) {
        int v = (tid >= off) ? s[tid - off] : 0;
        __syncthreads();
        s[tid] += v;
        __syncthreads();
    }
    if (i < N) {
        int excl = s[tid] - c + bsums[blockIdx.x];
        cursor[i] = excl;
        int4 ni;
        ni.x = excl;
        ni.y = c;
        ni.z = (int)__float_as_uint(rsqrtf((float)c + 1.0f));  // +1 self-loop
        ni.w = 0;
        nodeinfo[i] = ni;
    }
}

__global__ __launch_bounds__(256) void fill_part_kernel(
    const int* __restrict__ src, const int* __restrict__ dst,
    int* __restrict__ cursor, int* __restrict__ col, int E, int psz) {
    int part = blockIdx.x & 7, chunk = blockIdx.x >> 3;
    int i = chunk * 256 + threadIdx.x;
    if (i >= E) return;
    int d = __builtin_nontemporal_load(&dst[i]);
    if (d / psz == part) {
        int s = __builtin_nontemporal_load(&src[i]);
        int p = atomicAdd(&cursor[d], 1);
        col[p] = s;
    }
}

// ================= dual gather core =================
// TWO nodes per wave, interleaved: 2 independent load chains per lane -> 4+
// loads in flight, one node's VALU hides the other's latency. Self-loop rows
// added once, after the reduce. (r15 config — best measured.)
__device__ __forceinline__ void gather64_dual(
    const uint4* __restrict__ g4, const int* __restrict__ col,
    int beg0, int deg0, int c0, int n0,
    int beg1, int deg1, int c1, int n1,
    int N, int lane, float* t0, float* t1) {
    int eighth = lane >> 3, fo = lane & 7;
    float A0[8] = {}, A1[8] = {};
    int dmax = deg0 > deg1 ? deg0 : deg1;
    int base = 0;
    while (true) {
        int rm = dmax - base; if (rm > 64) rm = 64;
        int gm = (rm + 7) >> 3;
        for (int j = 0; j < gm; ++j) {
            int s0 = __shfl(c0, 8 * j + eighth, 64);
            int s1 = __shfl(c1, 8 * j + eighth, 64);
            uint4 v0 = g4[(size_t)s0 * 8 + fo];
            uint4 v1 = g4[(size_t)s1 * 8 + fo];
            acc8(A0, v0);
            acc8(A1, v1);
        }
        base += 64;
        if (base >= dmax) break;
        c0 = (lane < deg0 - base) ? __builtin_nontemporal_load(&col[beg0 + base + lane]) : N;
        c1 = (lane < deg1 - base) ? __builtin_nontemporal_load(&col[beg1 + base + lane]) : N;
    }
    // self-loop rows: added ONCE, after the reduce
    float sf0[8] = {}, sf1[8] = {};
    acc8(sf0, g4[(size_t)n0 * 8 + fo]);
    acc8(sf1, g4[(size_t)n1 * 8 + fo]);
#pragma unroll
    for (int k = 0; k < 8; ++k) {
        float s0 = A0[k], s1 = A1[k];
        s0 += __shfl_xor(s0, 8, 64);
        s1 += __shfl_xor(s1, 8, 64);
        s0 += __shfl_xor(s0, 16, 64);
        s1 += __shfl_xor(s1, 16, 64);
        s0 += __shfl_xor(s0, 32, 64);
        s1 += __shfl_xor(s1, 32, 64);
        t0[k] = s0 + sf0[k];
        t1[k] = s1 + sf1[k];
    }
}

// ================= conv1 GEMM: g = bf16((X@W)*dinv) =================

__global__ __launch_bounds__(256) void gemm_scale_kernel(
    const float* __restrict__ X, const float* __restrict__ W,
    const int4* __restrict__ nodeinfo, unsigned short* __restrict__ g, int N) {
    __shared__ float Ws[HID * HID];
    __shared__ float xs[4][HID];
    int tid = threadIdx.x;
    for (int i = tid; i < HID * HID; i += 256) Ws[i] = W[i];
    __syncthreads();
    int w = tid >> 6, c = tid & 63;
    float* xsw = xs[w];
    int ngrp = (N + 3) / 4;
    for (int grp = blockIdx.x; grp < ngrp; grp += gridDim.x) {
        int row = grp * 4 + w;
        if (row >= N) continue;
        xsw[c] = __builtin_nontemporal_load(&X[(size_t)row * HID + c]);
        float dn = __uint_as_float((unsigned)__builtin_amdgcn_readfirstlane(nodeinfo[row].z));
        float acc = 0.f;
#pragma unroll
        for (int k = 0; k < HID; ++k) acc = fmaf(xsw[k], Ws[k * HID + c], acc);
        __builtin_nontemporal_store(f2bf(acc * dn), &g[(size_t)row * HID + c]);
    }
}

// ---- register 8x8-block GEMM butterfly (r14-proven) ----
__device__ __forceinline__ float reggemm_butterfly(
    const unsigned* Wp, const float* o, int s) {
    float p[8] = {};
#pragma unroll
    for (int j = 0; j < 8; ++j) {
        float oj = o[j];
#pragma unroll
        for (int i2 = 0; i2 < 4; ++i2) {
            unsigned wv = Wp[j * 4 + i2];
            p[2 * i2]     = fmaf(oj, __uint_as_float(wv << 16), p[2 * i2]);
            p[2 * i2 + 1] = fmaf(oj, __uint_as_float(wv & 0xffff0000u), p[2 * i2 + 1]);
        }
    }
    bool b0 = (s & 1) != 0;
    float q1[4];
#pragma unroll
    for (int m = 0; m < 4; ++m) {
        float A = __shfl_xor(p[2 * m], 1, 64);
        float B = __shfl_xor(p[2 * m + 1], 1, 64);
        q1[m] = b0 ? (p[2 * m + 1] + B) : (p[2 * m] + A);
    }
    bool b1 = ((s >> 1) & 1) != 0;
    float q2[2];
#pragma unroll
    for (int m = 0; m < 2; ++m) {
        float A = __shfl_xor(q1[2 * m], 2, 64);
        float B = __shfl_xor(q1[2 * m + 1], 2, 64);
        q2[m] = b1 ? (q1[2 * m + 1] + B) : (q1[2 * m] + A);
    }
    bool b2 = ((s >> 2) & 1) != 0;
    float A = __shfl_xor(q2[0], 4, 64);
    float B = __shfl_xor(q2[1], 4, 64);
    return b2 ? (q2[1] + B) : (q2[0] + A);
}

// ================= fused aggregate + epilogue + next-conv GEMM (2 nodes/wave)

template <bool RELU>
__global__ __launch_bounds__(256, 4) void agg_gemm_kernel(
    const unsigned short* __restrict__ g_in, const int4* __restrict__ nodeinfo,
    const int* __restrict__ col, const float* __restrict__ bias,
    const float* __restrict__ W, unsigned short* __restrict__ g_out, int N) {
    int tid = threadIdx.x, w = tid >> 6, lane = tid & 63;
    int s = lane & 7;
    unsigned Wp[32];
#pragma unroll
    for (int j = 0; j < 8; ++j)
#pragma unroll
        for (int i2 = 0; i2 < 4; ++i2) {
            float w0 = W[(8 * s + j) * HID + 8 * (lane >> 3) + 2 * i2];
            float w1 = W[(8 * s + j) * HID + 8 * (lane >> 3) + 2 * i2 + 1];
            Wp[j * 4 + i2] = (unsigned)f2bf(w0) | ((unsigned)f2bf(w1) << 16);
        }
    float bb[8];
#pragma unroll
    for (int j = 0; j < 8; ++j) bb[j] = bias[8 * s + j];
    const uint4* g4 = (const uint4*)g_in;
    const int ngrp = (N + 7) / 8;  // 8 nodes per block-iteration (2 per wave)
    for (int grp = blockIdx.x; grp < ngrp; grp += gridDim.x) {
        int n0 = grp * 8 + w;
        int n1 = n0 + 4;
        if (n0 >= N) continue;
        bool has1 = n1 < N;
        int4 ni0 = nodeinfo[n0];
        int4 ni1 = has1 ? nodeinfo[n1] : ni0;
        int beg0 = __builtin_amdgcn_readfirstlane(ni0.x);
        int deg0 = __builtin_amdgcn_readfirstlane(ni0.y);
        float dn0 = __uint_as_float((unsigned)__builtin_amdgcn_readfirstlane(ni0.z));
        int beg1 = __builtin_amdgcn_readfirstlane(ni1.x);
        int deg1 = has1 ? __builtin_amdgcn_readfirstlane(ni1.y) : 0;
        float dn1 = __uint_as_float((unsigned)__builtin_amdgcn_readfirstlane(ni1.z));
        int c0 = (lane < deg0) ? __builtin_nontemporal_load(&col[beg0 + lane]) : N;
        int c1 = (lane < deg1) ? __builtin_nontemporal_load(&col[beg1 + lane]) : N;
        float t0[8], t1[8];
        gather64_dual(g4, col, beg0, deg0, c0, n0, beg1, deg1, c1, has1 ? n1 : N,
                      N, lane, t0, t1);
        float o[8];
#pragma unroll
        for (int j = 0; j < 8; ++j) {
            o[j] = fmaf(dn0, t0[j], bb[j]);
            if (RELU) o[j] = fmaxf(o[j], 0.f);
        }
        float r0 = reggemm_butterfly(Wp, o, s);
        __builtin_nontemporal_store(f2bf(r0 * dn0), &g_out[(size_t)n0 * HID + lane]);
        if (has1) {
#pragma unroll
            for (int j = 0; j < 8; ++j) {
                o[j] = fmaf(dn1, t1[j], bb[j]);
                if (RELU) o[j] = fmaxf(o[j], 0.f);
            }
            float r1 = reggemm_butterfly(Wp, o, s);
            __builtin_nontemporal_store(f2bf(r1 * dn1), &g_out[(size_t)n1 * HID + lane]);
        }
    }
}

// ================= final aggregate + bias + log_softmax (2 nodes/wave) =====

__device__ __forceinline__ void lsm_store(
    const float* t, float dn, const float* bb, int n, int lane, float* out) {
    int eighth = lane >> 3, fo = lane & 7;
    float v[8];
#pragma unroll
    for (int k = 0; k < 8; ++k) v[k] = fmaf(dn, t[k], bb[k]);
    float mx = v[0];
#pragma unroll
    for (int k = 1; k < 8; ++k) mx = fmaxf(mx, v[k]);
    mx = fmaxf(mx, __shfl_xor(mx, 1, 64));
    mx = fmaxf(mx, __shfl_xor(mx, 2, 64));
    mx = fmaxf(mx, __shfl_xor(mx, 4, 64));
    float sum = 0.f;
#pragma unroll
    for (int k = 0; k < 8; ++k) sum += expf(v[k] - mx);
    sum += __shfl_xor(sum, 1, 64);
    sum += __shfl_xor(sum, 2, 64);
    sum += __shfl_xor(sum, 4, 64);
    float ls = mx + logf(sum);
    if (eighth == 0) {
        f32x4 o0 = {v[0] - ls, v[1] - ls, v[2] - ls, v[3] - ls};
        f32x4 o1 = {v[4] - ls, v[5] - ls, v[6] - ls, v[7] - ls};
        f32x4* op = (f32x4*)out;
        __builtin_nontemporal_store(o0, &op[(size_t)n * 16 + 2 * fo]);
        __builtin_nontemporal_store(o1, &op[(size_t)n * 16 + 2 * fo + 1]);
    }
}

__global__ __launch_bounds__(256, 4) void agg_lsm_kernel(
    const unsigned short* __restrict__ g_in, const int4* __restrict__ nodeinfo,
    const int* __restrict__ col, const float* __restrict__ bias,
    float* __restrict__ out, int N) {
    int tid = threadIdx.x, w = tid >> 6, lane = tid & 63;
    int fo = lane & 7;
    const uint4* g4 = (const uint4*)g_in;
    float bb[8];
#pragma unroll
    for (int j = 0; j < 8; ++j) bb[j] = bias[8 * fo + j];
    const int ngrp = (N + 7) / 8;
    for (int grp = blockIdx.x; grp < ngrp; grp += gridDim.x) {
        int n0 = grp * 8 + w;
        int n1 = n0 + 4;
        if (n0 >= N) continue;
        bool has1 = n1 < N;
        int4 ni0 = nodeinfo[n0];
        int4 ni1 = has1 ? nodeinfo[n1] : ni0;
        int beg0 = __builtin_amdgcn_readfirstlane(ni0.x);
        int deg0 = __builtin_amdgcn_readfirstlane(ni0.y);
        float dn0 = __uint_as_float((unsigned)__builtin_amdgcn_readfirstlane(ni0.z));
        int beg1 = __builtin_amdgcn_readfirstlane(ni1.x);
        int deg1 = has1 ? __builtin_amdgcn_readfirstlane(ni1.y) : 0;
        float dn1 = __uint_as_float((unsigned)__builtin_amdgcn_readfirstlane(ni1.z));
        int c0 = (lane < deg0) ? __builtin_nontemporal_load(&col[beg0 + lane]) : N;
        int c1 = (lane < deg1) ? __builtin_nontemporal_load(&col[beg1 + lane]) : N;
        float t0[8], t1[8];
        gather64_dual(g4, col, beg0, deg0, c0, n0, beg1, deg1, c1, has1 ? n1 : N,
                      N, lane, t0, t1);
        lsm_store(t0, dn0, bb, n0, lane, out);
        if (has1) lsm_store(t1, dn1, bb, n1, lane, out);
    }
}

// ================= launcher =================

static inline size_t alignup(size_t x) { return (x + 255) & ~(size_t)255; }

extern "C" void kernel_launch(void* const* d_in, const int* in_sizes, int n_in,
                              void* d_out, int out_size, void* d_ws, size_t ws_size,
                              hipStream_t stream) {
    const float* x  = (const float*)d_in[0];
    const int*   ei = (const int*)d_in[1];
    const float* W1 = (const float*)d_in[2];
    const float* b1 = (const float*)d_in[3];
    const float* W2 = (const float*)d_in[4];
    const float* b2 = (const float*)d_in[5];

    const int N = in_sizes[0] / HID;  // 100000
    const int E = in_sizes[1] / 2;    // 1600000
    const int* src = ei;
    const int* dst = ei + E;

    const int nblk = (N + 255) / 256;  // 391 (<=512 required by scan)
    const int psz  = (N + 7) / 8;      // dst-range partition size

    char* w = (char*)d_ws;
    unsigned short* gA       = (unsigned short*)w; w += alignup((size_t)(N + 1) * HID * 2);
    unsigned short* gB       = (unsigned short*)w; w += alignup((size_t)(N + 1) * HID * 2);
    int4*           nodeinfo = (int4*)w;           w += alignup((size_t)N * 16);
    int*            cnt      = (int*)w;            w += alignup((size_t)N * 4);
    int*            cursor   = (int*)w;            w += alignup((size_t)N * 4);
    int*            col      = (int*)w;            w += alignup((size_t)E * 4);
    int*            bsums    = (int*)w;            w += alignup((size_t)nblk * 4);

    const int egrid  = (E + 255) / 256;
    const int gsgrid = 2048;  // grid-stride kernels

    // sentinel rows (index N) of both g buffers: zero once per launch
    (void)hipMemsetAsync(gA + (size_t)N * HID, 0, HID * sizeof(unsigned short), stream);
    (void)hipMemsetAsync(gB + (size_t)N * HID, 0, HID * sizeof(unsigned short), stream);

    // ---- CSR build (once; reused by all 3 convs) ----
    (void)hipMemsetAsync(cnt, 0, (size_t)N * sizeof(int), stream);
    hist_part_kernel<<<egrid * 8, 256, 0, stream>>>(dst, cnt, E, psz);
    bsum_kernel<<<nblk, 256, 0, stream>>>(cnt, bsums, N);
    scan_bsums_kernel<<<1, 512, 0, stream>>>(bsums, nblk);
    rowptr_kernel<<<nblk, 256, 0, stream>>>(cnt, bsums, nodeinfo, cursor, N);
    fill_part_kernel<<<egrid * 8, 256, 0, stream>>>(src, dst, cursor, col, E, psz);

    // ---- conv1 GEMM: gA = (x@W1)*dinv ----
    gemm_scale_kernel<<<gsgrid, 256, 0, stream>>>(x, W1, nodeinfo, gA, N);
    // ---- conv1 agg + b1 | conv2 GEMM: gB = ((agg(gA)+b1)@W1)*dinv ----
    agg_gemm_kernel<false><<<gsgrid, 256, 0, stream>>>(gA, nodeinfo, col, b1, W1, gB, N);
    // ---- conv2 agg + b1 + relu | conv3 GEMM: gA = (relu(agg(gB)+b1)@W2)*dinv ----
    agg_gemm_kernel<true><<<gsgrid, 256, 0, stream>>>(gB, nodeinfo, col, b1, W2, gA, N);
    // ---- conv3 agg + b2 + log_softmax -> d_out ----
    agg_lsm_kernel<<<gsgrid, 256, 0, stream>>>(gA, nodeinfo, col, b2, (float*)d_out, N);
}